// Round 15
// baseline (133.909 us; speedup 1.0000x reference)
//
#include <hip/hip_runtime.h>
#include <hip/hip_bf16.h>

// MHA b=2 t=2048 E=1024 h=16 d=64 (fp32 in/out).
// R15: QKV GEMM -> BK=32, 3-buffer depth-2 pipeline (84KB LDS), per-wave
//      counted vmcnt, XCD-swizzled grid (each XCD owns 2 n-cols -> W panels
//      L2-resident; depth-2 covers L2 latency).  Out-proj: + XCD swizzle.
// attn32 (R12, 46us), conv_all, merge: frozen.

#define HEADS 16
#define EMB   1024
#define HDIM  64
#define BB    2
#define TT    2048
#define QSCALE 0.18033688011112042f   // (1/8) * log2(e)

typedef __attribute__((ext_vector_type(8)))  short      bf16x8;
typedef __attribute__((ext_vector_type(8)))  _Float16   f16x8;
typedef __attribute__((ext_vector_type(4)))  float      f32x4;
typedef __attribute__((ext_vector_type(16))) float      f32x16;
typedef __attribute__((ext_vector_type(4)))  unsigned   u32x4;

__device__ __forceinline__ unsigned short f2bf(float f) {
    __hip_bfloat16 h = __float2bfloat16(f);
    return __builtin_bit_cast(unsigned short, h);
}
__device__ __forceinline__ float fexp2(float x) {
#if __has_builtin(__builtin_amdgcn_exp2f)
    return __builtin_amdgcn_exp2f(x);
#else
    return exp2f(x);
#endif
}
__device__ __forceinline__ unsigned pkrtz(float a, float b) {
    auto r = __builtin_amdgcn_cvt_pkrtz(a, b);
    return __builtin_bit_cast(unsigned, r);
}
__device__ __forceinline__ unsigned short f2h(float f) {
    return (unsigned short)(pkrtz(f, 0.f) & 0xffffu);
}
__device__ __forceinline__ float h2f(unsigned short u) {
    return (float)__builtin_bit_cast(_Float16, u);
}
__device__ __forceinline__ void gload_lds16(const void* g, void* l) {
    __builtin_amdgcn_global_load_lds(
        (const __attribute__((address_space(1))) void*)g,
        (__attribute__((address_space(3))) void*)l, 16, 0, 0);
}
// swizzled ushort index, [rows][64]-short tiles (128B rows, 16B blocks)
__device__ __forceinline__ int swzi(int row, int blk) {
    return row * 64 + ((blk ^ (row & 7)) << 3);
}
// swizzled ushort index, [rows][32]-short tiles (64B rows, 4x16B blocks):
// blk' = blk ^ ((row>>1)&3)  (even/odd rows split bank halves; 2-way max)
__device__ __forceinline__ int swz32(int row, int blk) {
    return row * 32 + ((blk ^ ((row >> 1) & 3)) << 3);
}
// v_permlane32_swap_b32: a' = {a.lo32, b.lo32}, b' = {a.hi32, b.hi32}
__device__ __forceinline__ void pl32swap(unsigned& a, unsigned& b) {
    asm("v_permlane32_swap_b32 %0, %1" : "+v"(a), "+v"(b));
}

// ---------------------------------------------------------------------------
// Fused conversions: blocks 0..2047 x->xb; 2048..5119 Wqkv->Wqb (permuted);
// 5120..6143 Wout->Wob.
// ---------------------------------------------------------------------------
__global__ __launch_bounds__(256)
void conv_all(const float* __restrict__ x,    unsigned short* __restrict__ xb,
              const float* __restrict__ Wqkv, unsigned short* __restrict__ Wqb,
              const float* __restrict__ Wout, unsigned short* __restrict__ Wob) {
    const int blk = blockIdx.x;
    if (blk < 2048) {
        const int i = blk * 256 + threadIdx.x;      // 8 floats / thread
        const float4 v0 = ((const float4*)x)[i * 2];
        const float4 v1 = ((const float4*)x)[i * 2 + 1];
        ushort4 a, b;
        a.x = f2bf(v0.x); a.y = f2bf(v0.y); a.z = f2bf(v0.z); a.w = f2bf(v0.w);
        b.x = f2bf(v1.x); b.y = f2bf(v1.y); b.z = f2bf(v1.z); b.w = f2bf(v1.w);
        ((ushort4*)xb)[i * 2]     = a;
        ((ushort4*)xb)[i * 2 + 1] = b;
    } else if (blk < 5120) {
        const int np = blk - 2048;
        const int ns = (np & 63) * 48 + (np >> 10) * 16 + ((np >> 6) & 15);
        const float4 v = ((const float4*)(Wqkv + (size_t)ns * 1024))[threadIdx.x];
        ushort4 u;
        u.x = f2bf(v.x); u.y = f2bf(v.y); u.z = f2bf(v.z); u.w = f2bf(v.w);
        ((ushort4*)(Wqb + (size_t)np * 1024))[threadIdx.x] = u;
    } else {
        const int np = blk - 5120;
        const float4 v = ((const float4*)(Wout + (size_t)np * 1024))[threadIdx.x];
        ushort4 u;
        u.x = f2bf(v.x); u.y = f2bf(v.y); u.z = f2bf(v.z); u.w = f2bf(v.w);
        ((ushort4*)(Wob + (size_t)np * 1024))[threadIdx.x] = u;
    }
}

// ---------------------------------------------------------------------------
// QKV GEMM, 256x192 tile, BK=32, 512 thr (8 waves 2m x 4n), 3-buffer depth-2
// pipeline, per-wave counted vmcnt (w<6 stages A+B: 4 loads; w>=6 A only: 2).
// XCD-swizzled 1D grid of 256: vb=(bid&7)*32+(bid>>3); n-col = vb>>4 (each
// XCD owns 2 n-cols -> 768KB W panel, L2-resident), m = vb&15.
// ---------------------------------------------------------------------------
__global__ __launch_bounds__(512, 2)
void gemm256_qkv(const unsigned short* __restrict__ Ag,
                 const unsigned short* __restrict__ Wg,
                 unsigned short* __restrict__ QKb,
                 unsigned short* __restrict__ Vt) {
    __shared__ __align__(16) unsigned short AbL[3][256 * 32];  // 16KB x3
    __shared__ __align__(16) unsigned short BbL[3][192 * 32];  // 12KB x3

    const int tid = threadIdx.x, lane = tid & 63, w = tid >> 6;   // w 0..7
    const int bid = blockIdx.x;
    const int vb  = (bid & 7) * 32 + (bid >> 3);
    const int n0  = (vb >> 4) * 192;
    const int m0  = (vb & 15) * 256;
    const int wm = (w >> 2) * 128;        // 0 / 128
    const int wn = (w & 3) * 48;          // 0 / 48 / 96 / 144
    const int r16 = lane & 15, g = lane >> 4, gq = g * 4;

    f32x4 acc[8][3];
    #pragma unroll
    for (int i = 0; i < 8; ++i)
        #pragma unroll
        for (int j = 0; j < 3; ++j)
            acc[i][j] = (f32x4){0.f, 0.f, 0.f, 0.f};

    // staging: one gload covers 16 rows x 64B; lane -> dest row lane>>2,
    // dest blk lane&3; src col = inverse-swizzled block.
    const int drow = lane >> 2;                         // 0..15
    const int sblk = (lane & 3) ^ ((drow >> 1) & 3);    // involution
    const int scol = sblk << 3;                         // shorts
    const unsigned short* Asrc = Ag + (size_t)(m0 + w * 32 + drow) * 1024 + scol;
    const unsigned short* Bsrc = Wg + (size_t)(n0 + w * 32 + drow) * 1024 + scol;

#define STAGE256(BUF, K0)                                                   \
    do {                                                                    \
        gload_lds16(Asrc + (K0),             &AbL[BUF][(w * 32) * 32]);     \
        gload_lds16(Asrc + (K0) + 16 * 1024, &AbL[BUF][(w * 32 + 16) * 32]);\
        if (w < 6) {                                                        \
            gload_lds16(Bsrc + (K0),             &BbL[BUF][(w * 32) * 32]); \
            gload_lds16(Bsrc + (K0) + 16 * 1024, &BbL[BUF][(w * 32 + 16) * 32]); \
        }                                                                   \
    } while (0)

    STAGE256(0, 0);
    STAGE256(1, 32);

    int cur = 0;
    for (int kt = 0; kt < 32; ++kt) {
        if (kt < 31) {
            if (w < 6) asm volatile("s_waitcnt vmcnt(4)" ::: "memory");
            else       asm volatile("s_waitcnt vmcnt(2)" ::: "memory");
        } else {
            asm volatile("s_waitcnt vmcnt(0)" ::: "memory");
        }
        __builtin_amdgcn_s_barrier();
        if (kt < 30) {
            const int nb = (cur + 2) % 3;
            STAGE256(nb, (kt + 2) * 32);
        }

        const unsigned short* Ab = &AbL[cur][0];
        const unsigned short* Bb = &BbL[cur][0];
        bf16x8 bfr[3];
        #pragma unroll
        for (int ni = 0; ni < 3; ++ni)
            bfr[ni] = *(const bf16x8*)&Bb[swz32(wn + ni * 16 + r16, g)];
        __builtin_amdgcn_s_setprio(1);
        #pragma unroll
        for (int mi = 0; mi < 8; ++mi) {
            const bf16x8 xf = *(const bf16x8*)&Ab[swz32(wm + mi * 16 + r16, g)];
            #pragma unroll
            for (int ni = 0; ni < 3; ++ni)
                acc[mi][ni] = __builtin_amdgcn_mfma_f32_16x16x32_bf16(
                    bfr[ni], xf, acc[mi][ni], 0, 0, 0);
        }
        __builtin_amdgcn_s_setprio(0);

        cur = (cur + 1) % 3;
    }
#undef STAGE256

    // epilogue: per-ni region select (16 | 1024 so each frag is uniform)
    #pragma unroll
    for (int ni = 0; ni < 3; ++ni) {
        const int npb = n0 + wn + ni * 16;   // frag n-base (16-aligned)
        if (npb < 2048) {
            const float qs = npb < 1024 ? QSCALE : 1.0f;
            #pragma unroll
            for (int mi = 0; mi < 8; ++mi) {
                const int m = m0 + wm + mi * 16 + r16;
                ushort4 u;
                u.x = f2bf(acc[mi][ni][0] * qs); u.y = f2bf(acc[mi][ni][1] * qs);
                u.z = f2bf(acc[mi][ni][2] * qs); u.w = f2bf(acc[mi][ni][3] * qs);
                *(ushort4*)&QKb[(size_t)m * 2048 + npb + gq] = u;
            }
        } else {
            #pragma unroll
            for (int mi = 0; mi < 8; ++mi) {
                const int m  = m0 + wm + mi * 16 + r16;
                const int b  = m >> 11, tt = m & 2047;
                const int nv0 = npb - 2048 + gq;
                #pragma unroll
                for (int j = 0; j < 4; ++j) {
                    const int nv = nv0 + j, h = nv >> 6, d = nv & 63;
                    Vt[(((size_t)(b * HEADS + h)) * HDIM + d) * TT + tt] =
                        f2h(acc[mi][ni][j]);
                }
            }
        }
    }
}

// ---------------------------------------------------------------------------
// Out-proj GEMM (R13 128^2, 2-buffer 2-phase) + XCD-swizzled 1D grid of 256:
// vb=(bid&7)*32+(bid>>3); n0=(vb>>5)*128 (XCD owns whole n-col), m0=(vb&31)*128.
// ---------------------------------------------------------------------------
__global__ __launch_bounds__(256)
void gemm_bf16(const unsigned short* __restrict__ Ag,
               const unsigned short* __restrict__ Wg,
               float* __restrict__ Cout) {
    __shared__ __align__(16) unsigned short AbL[2][128 * 32];
    __shared__ __align__(16) unsigned short WbL[2][128 * 32];

    const int tid = threadIdx.x, lane = tid & 63, w = tid >> 6;
    const int bid = blockIdx.x;
    const int vb  = (bid & 7) * 32 + (bid >> 3);
    const int n0  = (vb >> 5) * 128;
    const int m0  = (vb & 31) * 128;
    const int wn = (w >> 1) * 64, wm = (w & 1) * 64;
    const int r16 = lane & 15, g = lane >> 4;
    const int goff = ((g ^ ((r16 >> 1) & 3)) << 3);

    f32x4 acc[4][4];
    #pragma unroll
    for (int i = 0; i < 4; ++i)
        #pragma unroll
        for (int j = 0; j < 4; ++j)
            acc[i][j] = (f32x4){0.f, 0.f, 0.f, 0.f};

    const int srow = w * 16 + (lane >> 2);
    const int scol = ((lane & 3) ^ ((lane >> 3) & 3)) << 3;
    const int sdst = (w * 16) * 32;
    const unsigned short* Asrc = Ag + (size_t)(m0 + srow) * 1024 + scol;
    const unsigned short* Wsrc = Wg + (size_t)(n0 + srow) * 1024 + scol;

#define STAGE(AB, WB, K0)                                            \
    do {                                                             \
        gload_lds16(Asrc + (K0),              (AB) + sdst);          \
        gload_lds16(Asrc + (K0) + 64 * 1024,  (AB) + sdst + 2048);   \
        gload_lds16(Wsrc + (K0),              (WB) + sdst);          \
        gload_lds16(Wsrc + (K0) + 64 * 1024,  (WB) + sdst + 2048);   \
    } while (0)

    unsigned short *pa0 = &AbL[0][0], *pa1 = &AbL[1][0];
    unsigned short *pw0 = &WbL[0][0], *pw1 = &WbL[1][0];

    STAGE(pa0, pw0, 0);

    for (int kt = 0; kt < 32; ++kt) {
        asm volatile("s_waitcnt vmcnt(0)" ::: "memory");
        __builtin_amdgcn_s_barrier();
        if (kt < 31) STAGE(pa1, pw1, (kt + 1) * 32);

        bf16x8 xf[4];
        #pragma unroll
        for (int mi = 0; mi < 4; ++mi)
            xf[mi] = *(const bf16x8*)&pa0[(wm + mi * 16 + r16) * 32 + goff];
        __builtin_amdgcn_s_setprio(1);
        #pragma unroll
        for (int ni = 0; ni < 4; ++ni) {
            const bf16x8 wf = *(const bf16x8*)&pw0[(wn + ni * 16 + r16) * 32 + goff];
            #pragma unroll
            for (int mi = 0; mi < 4; ++mi)
                acc[ni][mi] = __builtin_amdgcn_mfma_f32_16x16x32_bf16(
                    wf, xf[mi], acc[ni][mi], 0, 0, 0);
        }
        __builtin_amdgcn_s_setprio(0);

        unsigned short* t;
        t = pa0; pa0 = pa1; pa1 = t;
        t = pw0; pw0 = pw1; pw1 = t;
    }
#undef STAGE

    const int gq = g * 4;
    #pragma unroll
    for (int ni = 0; ni < 4; ++ni)
        #pragma unroll
        for (int mi = 0; mi < 4; ++mi) {
            const int m = m0 + wm + mi * 16 + r16;
            *(f32x4*)&Cout[(size_t)m * 1024 + (n0 + wn + ni * 16 + gq)] =
                acc[ni][mi];
        }
}

// ---------------------------------------------------------------------------
// Flash attention, 32x32x16 MFMA, 2-way key split (R12-verified: 46us).
// ---------------------------------------------------------------------------
__global__ __launch_bounds__(256, 4)
void attn32(const unsigned short* __restrict__ QKb,
            const unsigned short* __restrict__ Vt,
            unsigned short* __restrict__ PO0,
            unsigned short* __restrict__ PO1,
            float* __restrict__ PL0,
            float* __restrict__ PL1) {
    __shared__ __align__(16) unsigned short Ks[2][64 * 64];
    __shared__ __align__(16) unsigned short Vs[2][64 * 64];

    const int tid = threadIdx.x, lane = tid & 63, w = tid >> 6;
    const int l31 = lane & 31, hi = lane >> 5;
    const int bid = blockIdx.x + 32 * blockIdx.y + 512 * blockIdx.z;  // 0..1023
    const int vb  = (bid & 7) * 128 + (bid >> 3);
    const int qt  = vb & 15, kh = (vb >> 4) & 1;
    const int h   = (vb >> 5) & 15, b = vb >> 9;
    const int kbase = kh * 1024;
    const unsigned short* Vsrc = Vt + (size_t)(b * HEADS + h) * HDIM * TT;
    unsigned short* PO = kh ? PO1 : PO0;
    float*          PL = kh ? PL1 : PL0;

    bf16x8 qf[4];
    {
        const unsigned short* qrow =
            QKb + ((size_t)(b * TT + qt * 128 + w * 32 + l31)) * 2048 + h * HDIM;
        #pragma unroll
        for (int dc = 0; dc < 4; ++dc)
            qf[dc] = *(const bf16x8*)(qrow + dc * 16 + hi * 8);
    }

    const f32x16 zz = {};
    f32x16 o0 = {}, o1 = {};
    float lrun = 0.f;

    const int srl = lane >> 3;
    const int scb = lane & 7;
    const int cbs = (scb ^ srl) << 3;
    const int rl0 = w * 16 + srl;
    const unsigned short* kp0 =
        QKb + (size_t)(b * TT + kbase + rl0) * 2048 + 1024 + h * HDIM + cbs;
    const unsigned short* kp1 = kp0 + (size_t)8 * 2048;
    const unsigned short* vp0 = Vsrc + (size_t)rl0 * TT + kbase + cbs;
    const unsigned short* vp1 = vp0 + (size_t)8 * TT;
    unsigned short* const kd0 = &Ks[0][(w * 16) * 64];
    unsigned short* const kd1 = &Ks[1][(w * 16) * 64];
    unsigned short* const vd0 = &Vs[0][(w * 16) * 64];
    unsigned short* const vd1 = &Vs[1][(w * 16) * 64];

#define STAGE(KD, VD)                                                  \
    do {                                                               \
        gload_lds16(kp0, (KD));        gload_lds16(kp1, (KD) + 512);   \
        gload_lds16(vp0, (VD));        gload_lds16(vp1, (VD) + 512);   \
        kp0 += 64 * 2048; kp1 += 64 * 2048; vp0 += 64; vp1 += 64;      \
    } while (0)

    STAGE(kd0, vd0);

    for (int jt = 0; jt < 16; ++jt) {
        const int bb = jt & 1;
        __syncthreads();
        if (jt < 15) {
            if (bb) STAGE(kd0, vd0); else STAGE(kd1, vd1);
        }
        const unsigned short* KsB = &Ks[bb][0];
        const unsigned short* VsB = &Vs[bb][0];

        f32x16 stA, stB;
        __builtin_amdgcn_s_setprio(1);
        #pragma unroll
        for (int dc = 0; dc < 4; ++dc) {
            const bf16x8 kaA = *(const bf16x8*)&KsB[swzi(l31,      dc * 2 + hi)];
            const bf16x8 kaB = *(const bf16x8*)&KsB[swzi(32 + l31, dc * 2 + hi)];
            if (dc == 0) {
                stA = __builtin_amdgcn_mfma_f32_32x32x16_bf16(kaA, qf[0], zz, 0, 0, 0);
                stB = __builtin_amdgcn_mfma_f32_32x32x16_bf16(kaB, qf[0], zz, 0, 0, 0);
            } else {
                stA = __builtin_amdgcn_mfma_f32_32x32x16_bf16(kaA, qf[dc], stA, 0, 0, 0);
                stB = __builtin_amdgcn_mfma_f32_32x32x16_bf16(kaB, qf[dc], stB, 0, 0, 0);
            }
        }
        __builtin_amdgcn_s_setprio(0);

        #pragma unroll
        for (int x = 0; x < 2; ++x) {
            const f32x16& st = x ? stB : stA;
            float sum;
            unsigned wd[8];
            #pragma unroll
            for (int c = 0; c < 4; ++c) {
                const float e0 = fexp2(st[4 * c + 0]);
                const float e1 = fexp2(st[4 * c + 1]);
                const float e2 = fexp2(st[4 * c + 2]);
                const float e3 = fexp2(st[4 * c + 3]);
                const float s4 = (e0 + e1) + (e2 + e3);
                sum = c ? sum + s4 : s4;
                wd[2 * c]     = pkrtz(e0, e1);
                wd[2 * c + 1] = pkrtz(e2, e3);
            }
            lrun += sum;

            unsigned a0 = wd[0], a2 = wd[2];  pl32swap(a0, a2);
            unsigned a1 = wd[1], a3 = wd[3];  pl32swap(a1, a3);
            unsigned b0 = wd[4], b2 = wd[6];  pl32swap(b0, b2);
            unsigned b1 = wd[5], b3 = wd[7];  pl32swap(b1, b3);
            const u32x4 fva = {a0, a1, a2, a3};
            const u32x4 fvb = {b0, b1, b2, b3};
            const f16x8 pa0 = __builtin_bit_cast(f16x8, fva);
            const f16x8 pa1 = __builtin_bit_cast(f16x8, fvb);

            const int f0 = 2 * x;
            __builtin_amdgcn_s_setprio(1);
            {
                const f16x8 vb00 = *(const f16x8*)&VsB[swzi(l31,      f0 * 2 + hi)];
                const f16x8 vb01 = *(const f16x8*)&VsB[swzi(32 + l31, f0 * 2 + hi)];
                o0 = __builtin_amdgcn_mfma_f32_32x32x16_f16(pa0, vb00, o0, 0, 0, 0);
                o1 = __builtin_amdgcn_mfma_f32_32x32x16_f16(pa0, vb01, o1, 0, 0, 0);
                const f16x8 vb10 = *(const f16x8*)&VsB[swzi(l31,      (f0 + 1) * 2 + hi)];
                const f16x8 vb11 = *(const f16x8*)&VsB[swzi(32 + l31, (f0 + 1) * 2 + hi)];
                o0 = __builtin_amdgcn_mfma_f32_32x32x16_f16(pa1, vb10, o0, 0, 0, 0);
                o1 = __builtin_amdgcn_mfma_f32_32x32x16_f16(pa1, vb11, o1, 0, 0, 0);
            }
            __builtin_amdgcn_s_setprio(0);
        }
    }
#undef STAGE

    lrun += __shfl_xor(lrun, 32);
    const float inv = 1.0f / lrun;
    #pragma unroll
    for (int r = 0; r < 16; ++r) {
        const int qr = (r & 3) + 8 * (r >> 2) + 4 * hi;
        const float ir = __shfl(inv, qr);
        const int q = qt * 128 + w * 32 + qr;
        unsigned short* dst = PO + ((size_t)(b * TT + q)) * EMB + h * HDIM + l31;
        dst[0]  = f2h(o0[r] * ir);
        dst[32] = f2h(o1[r] * ir);
    }
    if (!hi) {
        const int q = qt * 128 + w * 32 + l31;
        PL[((size_t)(b * HEADS + h)) * TT + q] = lrun;
    }
}

// ---------------------------------------------------------------------------
// Merge the two key-half partials: AO = (Oa*la + Ob*lb) / (la+lb), bf16 out.
// ---------------------------------------------------------------------------
__global__ __launch_bounds__(256)
void merge_attn(const unsigned short* __restrict__ PO0,
                const unsigned short* __restrict__ PO1,
                const float* __restrict__ PL0,
                const float* __restrict__ PL1,
                unsigned short* __restrict__ AOb) {
    const int i = blockIdx.x * 256 + threadIdx.x;   // 4-elem group
    const int tg  = i >> 8;            // b*2048 + t
    const int col = (i & 255) * 4;
    const int h   = col >> 6;
    const int b   = tg >> 11, t = tg & 2047;

    const float la = PL0[((size_t)(b * HEADS + h)) * TT + t];
    const float lb = PL1[((size_t)(b * HEADS + h)) * TT + t];
    const float inv = 1.0f / (la + lb);
    const float wa = la * inv, wb = lb * inv;

    const ushort4 a = ((const ushort4*)PO0)[i];
    const ushort4 c = ((const ushort4*)PO1)[i];
    ushort4 o;
    o.x = f2bf(h2f(a.x) * wa + h2f(c.x) * wb);
    o.y = f2bf(h2f(a.y) * wa + h2f(c.y) * wb);
    o.z = f2bf(h2f(a.z) * wa + h2f(c.z) * wb);
    o.w = f2bf(h2f(a.w) * wa + h2f(c.w) * wb);
    ((ushort4*)AOb)[i] = o;
}

// ---------------------------------------------------------------------------
extern "C" void kernel_launch(void* const* d_in, const int* in_sizes, int n_in,
                              void* d_out, int out_size, void* d_ws, size_t ws_size,
                              hipStream_t stream) {
    const float* x    = (const float*)d_in[0];   // [2,2048,1024]
    const float* Wqkv = (const float*)d_in[1];   // [3072,1024]
    const float* Wout = (const float*)d_in[2];   // [1024,1024]
    float* out = (float*)d_out;

    unsigned short* Wqb = (unsigned short*)d_ws;   // 3145728 (permuted)
    unsigned short* Wob = Wqb + 3145728;           // 1048576
    unsigned short* xb  = Wob + 1048576;           // 4194304 (aliased by AOb)
    unsigned short* QKb = xb  + 4194304;           // 8388608 [b*t][2048] bf16
    unsigned short* Vt  = QKb + 8388608;           // 4194304 [b,h,d,t] fp16
    unsigned short* PO0 = Vt  + 4194304;           // 4194304 fp16 partial O
    unsigned short* PO1 = PO0 + 4194304;           // 4194304 fp16 partial O
    float*          PL0 = (float*)(PO1 + 4194304); // 65536 f32
    float*          PL1 = PL0 + 65536;             // 65536 f32
    unsigned short* AOb = xb;                      // reuse xb (dead after QKV)

    conv_all<<<6144, 256, 0, stream>>>(x, xb, Wqkv, Wqb, Wout, Wob);

    gemm256_qkv<<<256, 512, 0, stream>>>(xb, Wqb, QKb, Vt);

    attn32<<<dim3(32, 16, 2), 256, 0, stream>>>(QKb, Vt, PO0, PO1, PL0, PL1);

    merge_attn<<<4096, 256, 0, stream>>>(PO0, PO1, PL0, PL1, AOb);

    gemm_bf16<<<256, 256, 0, stream>>>(AOb, Wob, out);
}

// Round 16
// 129.805 us; speedup vs baseline: 1.0316x; 1.0316x over previous
//
#include <hip/hip_runtime.h>
#include <hip/hip_bf16.h>

// MHA b=2 t=2048 E=1024 h=16 d=64 (fp32 in/out).
// R16: GEMMs = R9's proven 3-buffer depth-2 counted-vmcnt 128^2 kernel
//      + XCD-swizzled 1D grids (QKV: each XCD owns 3 n-cols; out-proj: 1).
//      First round combining TLP (3 blocks/CU) + depth-2 ILP + L2-resident W.
// attn32 (R12, 46us), conv_all, merge: frozen.

#define HEADS 16
#define EMB   1024
#define HDIM  64
#define BB    2
#define TT    2048
#define QSCALE 0.18033688011112042f   // (1/8) * log2(e)

typedef __attribute__((ext_vector_type(8)))  short      bf16x8;
typedef __attribute__((ext_vector_type(8)))  _Float16   f16x8;
typedef __attribute__((ext_vector_type(4)))  float      f32x4;
typedef __attribute__((ext_vector_type(16))) float      f32x16;
typedef __attribute__((ext_vector_type(4)))  unsigned   u32x4;

__device__ __forceinline__ unsigned short f2bf(float f) {
    __hip_bfloat16 h = __float2bfloat16(f);
    return __builtin_bit_cast(unsigned short, h);
}
__device__ __forceinline__ float fexp2(float x) {
#if __has_builtin(__builtin_amdgcn_exp2f)
    return __builtin_amdgcn_exp2f(x);
#else
    return exp2f(x);
#endif
}
__device__ __forceinline__ unsigned pkrtz(float a, float b) {
    auto r = __builtin_amdgcn_cvt_pkrtz(a, b);
    return __builtin_bit_cast(unsigned, r);
}
__device__ __forceinline__ unsigned short f2h(float f) {
    return (unsigned short)(pkrtz(f, 0.f) & 0xffffu);
}
__device__ __forceinline__ float h2f(unsigned short u) {
    return (float)__builtin_bit_cast(_Float16, u);
}
__device__ __forceinline__ void gload_lds16(const void* g, void* l) {
    __builtin_amdgcn_global_load_lds(
        (const __attribute__((address_space(1))) void*)g,
        (__attribute__((address_space(3))) void*)l, 16, 0, 0);
}
// swizzled ushort index, [rows][64]-short tiles (128B rows, 16B blocks)
__device__ __forceinline__ int swzi(int row, int blk) {
    return row * 64 + ((blk ^ (row & 7)) << 3);
}
// v_permlane32_swap_b32: a' = {a.lo32, b.lo32}, b' = {a.hi32, b.hi32}
__device__ __forceinline__ void pl32swap(unsigned& a, unsigned& b) {
    asm("v_permlane32_swap_b32 %0, %1" : "+v"(a), "+v"(b));
}

// ---------------------------------------------------------------------------
// Fused conversions: blocks 0..2047 x->xb; 2048..5119 Wqkv->Wqb (permuted);
// 5120..6143 Wout->Wob.
// ---------------------------------------------------------------------------
__global__ __launch_bounds__(256)
void conv_all(const float* __restrict__ x,    unsigned short* __restrict__ xb,
              const float* __restrict__ Wqkv, unsigned short* __restrict__ Wqb,
              const float* __restrict__ Wout, unsigned short* __restrict__ Wob) {
    const int blk = blockIdx.x;
    if (blk < 2048) {
        const int i = blk * 256 + threadIdx.x;      // 8 floats / thread
        const float4 v0 = ((const float4*)x)[i * 2];
        const float4 v1 = ((const float4*)x)[i * 2 + 1];
        ushort4 a, b;
        a.x = f2bf(v0.x); a.y = f2bf(v0.y); a.z = f2bf(v0.z); a.w = f2bf(v0.w);
        b.x = f2bf(v1.x); b.y = f2bf(v1.y); b.z = f2bf(v1.z); b.w = f2bf(v1.w);
        ((ushort4*)xb)[i * 2]     = a;
        ((ushort4*)xb)[i * 2 + 1] = b;
    } else if (blk < 5120) {
        const int np = blk - 2048;
        const int ns = (np & 63) * 48 + (np >> 10) * 16 + ((np >> 6) & 15);
        const float4 v = ((const float4*)(Wqkv + (size_t)ns * 1024))[threadIdx.x];
        ushort4 u;
        u.x = f2bf(v.x); u.y = f2bf(v.y); u.z = f2bf(v.z); u.w = f2bf(v.w);
        ((ushort4*)(Wqb + (size_t)np * 1024))[threadIdx.x] = u;
    } else {
        const int np = blk - 5120;
        const float4 v = ((const float4*)(Wout + (size_t)np * 1024))[threadIdx.x];
        ushort4 u;
        u.x = f2bf(v.x); u.y = f2bf(v.y); u.z = f2bf(v.z); u.w = f2bf(v.w);
        ((ushort4*)(Wob + (size_t)np * 1024))[threadIdx.x] = u;
    }
}

// ---------------------------------------------------------------------------
// D[n][m] GEMM, 128x128 tile, BK=32, 3-buffer depth-2 pipeline with counted
// vmcnt(4) (R9-proven loop).  XCD-swizzled 1D grid:
//   EPI=1 (QKV, 768 blocks): xcd=bid&7 owns n-cols {3*xcd..3*xcd+2};
//         loc=bid>>3: n0=(xcd*3+(loc>>5))*128, m0=(loc&31)*128.
//   EPI=0 (out-proj, 256 blocks): n0=(bid&7)*128, m0=(bid>>3)*128.
// EPI=1 epilogue: n<1024 Q(*QSCALE)->QKb, n<2048 K->QKb, else V->Vt fp16.
// ---------------------------------------------------------------------------
template<int EPI>
__global__ __launch_bounds__(256)
void gemm_bf16(const unsigned short* __restrict__ Ag,
               const unsigned short* __restrict__ Wg,
               float* __restrict__ Cout,
               unsigned short* __restrict__ QKb,
               unsigned short* __restrict__ Vt) {
    __shared__ __align__(16) unsigned short AbL[3][128 * 32];
    __shared__ __align__(16) unsigned short WbL[3][128 * 32];

    const int tid = threadIdx.x, lane = tid & 63, w = tid >> 6;
    const int bid = blockIdx.x;
    int n0, m0;
    if (EPI == 1) {
        const int xcd = bid & 7, loc = bid >> 3;
        n0 = (xcd * 3 + (loc >> 5)) * 128;
        m0 = (loc & 31) * 128;
    } else {
        n0 = (bid & 7) * 128;
        m0 = (bid >> 3) * 128;
    }
    const int wn = (w >> 1) * 64, wm = (w & 1) * 64;
    const int r16 = lane & 15, g = lane >> 4;
    const int goff = ((g ^ ((r16 >> 1) & 3)) << 3);

    f32x4 acc[4][4];
    #pragma unroll
    for (int i = 0; i < 4; ++i)
        #pragma unroll
        for (int j = 0; j < 4; ++j)
            acc[i][j] = (f32x4){0.f, 0.f, 0.f, 0.f};

    const int srow = w * 16 + (lane >> 2);
    const int scol = ((lane & 3) ^ ((lane >> 3) & 3)) << 3;
    const int sdst = (w * 16) * 32;
    const unsigned short* Asrc = Ag + (size_t)(m0 + srow) * 1024 + scol;
    const unsigned short* Wsrc = Wg + (size_t)(n0 + srow) * 1024 + scol;

#define STAGE(AB, WB, K0)                                            \
    do {                                                             \
        gload_lds16(Asrc + (K0),              (AB) + sdst);          \
        gload_lds16(Asrc + (K0) + 64 * 1024,  (AB) + sdst + 2048);   \
        gload_lds16(Wsrc + (K0),              (WB) + sdst);          \
        gload_lds16(Wsrc + (K0) + 64 * 1024,  (WB) + sdst + 2048);   \
    } while (0)

    unsigned short *pa0 = &AbL[0][0], *pa1 = &AbL[1][0], *pa2 = &AbL[2][0];
    unsigned short *pw0 = &WbL[0][0], *pw1 = &WbL[1][0], *pw2 = &WbL[2][0];

    STAGE(pa0, pw0, 0);
    STAGE(pa1, pw1, 32);

    for (int kt = 0; kt < 32; ++kt) {
        if (kt < 31) asm volatile("s_waitcnt vmcnt(4)" ::: "memory");
        else         asm volatile("s_waitcnt vmcnt(0)" ::: "memory");
        __builtin_amdgcn_s_barrier();
        if (kt < 30) STAGE(pa2, pw2, (kt + 2) * 32);

        bf16x8 xf[4];
        #pragma unroll
        for (int mi = 0; mi < 4; ++mi)
            xf[mi] = *(const bf16x8*)&pa0[(wm + mi * 16 + r16) * 32 + goff];
        __builtin_amdgcn_s_setprio(1);
        #pragma unroll
        for (int ni = 0; ni < 4; ++ni) {
            const bf16x8 wf = *(const bf16x8*)&pw0[(wn + ni * 16 + r16) * 32 + goff];
            #pragma unroll
            for (int mi = 0; mi < 4; ++mi)
                acc[ni][mi] = __builtin_amdgcn_mfma_f32_16x16x32_bf16(
                    wf, xf[mi], acc[ni][mi], 0, 0, 0);
        }
        __builtin_amdgcn_s_setprio(0);

        unsigned short* t;
        t = pa0; pa0 = pa1; pa1 = pa2; pa2 = t;
        t = pw0; pw0 = pw1; pw1 = pw2; pw2 = t;
    }
#undef STAGE

    const int gq = g * 4;
    if (EPI == 0) {
        #pragma unroll
        for (int ni = 0; ni < 4; ++ni)
            #pragma unroll
            for (int mi = 0; mi < 4; ++mi) {
                const int m = m0 + wm + mi * 16 + r16;
                *(f32x4*)&Cout[(size_t)m * 1024 + (n0 + wn + ni * 16 + gq)] =
                    acc[ni][mi];
            }
    } else if (n0 < 2048) {
        #pragma unroll
        for (int ni = 0; ni < 4; ++ni) {
            const float qs = (n0 + wn + ni * 16) < 1024 ? QSCALE : 1.0f;
            #pragma unroll
            for (int mi = 0; mi < 4; ++mi) {
                const int m  = m0 + wm + mi * 16 + r16;
                const int np = n0 + wn + ni * 16 + gq;
                ushort4 u;
                u.x = f2bf(acc[ni][mi][0] * qs); u.y = f2bf(acc[ni][mi][1] * qs);
                u.z = f2bf(acc[ni][mi][2] * qs); u.w = f2bf(acc[ni][mi][3] * qs);
                *(ushort4*)&QKb[(size_t)m * 2048 + np] = u;
            }
        }
    } else {
        #pragma unroll
        for (int ni = 0; ni < 4; ++ni)
            #pragma unroll
            for (int mi = 0; mi < 4; ++mi) {
                const int m  = m0 + wm + mi * 16 + r16;
                const int b  = m >> 11, tt = m & 2047;
                const int nv0 = (n0 - 2048) + wn + ni * 16 + gq;
                #pragma unroll
                for (int j = 0; j < 4; ++j) {
                    const int nv = nv0 + j, h = nv >> 6, d = nv & 63;
                    Vt[(((size_t)(b * HEADS + h)) * HDIM + d) * TT + tt] =
                        f2h(acc[ni][mi][j]);
                }
            }
    }
}

// ---------------------------------------------------------------------------
// Flash attention, 32x32x16 MFMA, 2-way key split (R12-verified: 46us).
// ---------------------------------------------------------------------------
__global__ __launch_bounds__(256, 4)
void attn32(const unsigned short* __restrict__ QKb,
            const unsigned short* __restrict__ Vt,
            unsigned short* __restrict__ PO0,
            unsigned short* __restrict__ PO1,
            float* __restrict__ PL0,
            float* __restrict__ PL1) {
    __shared__ __align__(16) unsigned short Ks[2][64 * 64];
    __shared__ __align__(16) unsigned short Vs[2][64 * 64];

    const int tid = threadIdx.x, lane = tid & 63, w = tid >> 6;
    const int l31 = lane & 31, hi = lane >> 5;
    const int bid = blockIdx.x + 32 * blockIdx.y + 512 * blockIdx.z;  // 0..1023
    const int vb  = (bid & 7) * 128 + (bid >> 3);
    const int qt  = vb & 15, kh = (vb >> 4) & 1;
    const int h   = (vb >> 5) & 15, b = vb >> 9;
    const int kbase = kh * 1024;
    const unsigned short* Vsrc = Vt + (size_t)(b * HEADS + h) * HDIM * TT;
    unsigned short* PO = kh ? PO1 : PO0;
    float*          PL = kh ? PL1 : PL0;

    bf16x8 qf[4];
    {
        const unsigned short* qrow =
            QKb + ((size_t)(b * TT + qt * 128 + w * 32 + l31)) * 2048 + h * HDIM;
        #pragma unroll
        for (int dc = 0; dc < 4; ++dc)
            qf[dc] = *(const bf16x8*)(qrow + dc * 16 + hi * 8);
    }

    const f32x16 zz = {};
    f32x16 o0 = {}, o1 = {};
    float lrun = 0.f;

    const int srl = lane >> 3;
    const int scb = lane & 7;
    const int cbs = (scb ^ srl) << 3;
    const int rl0 = w * 16 + srl;
    const unsigned short* kp0 =
        QKb + (size_t)(b * TT + kbase + rl0) * 2048 + 1024 + h * HDIM + cbs;
    const unsigned short* kp1 = kp0 + (size_t)8 * 2048;
    const unsigned short* vp0 = Vsrc + (size_t)rl0 * TT + kbase + cbs;
    const unsigned short* vp1 = vp0 + (size_t)8 * TT;
    unsigned short* const kd0 = &Ks[0][(w * 16) * 64];
    unsigned short* const kd1 = &Ks[1][(w * 16) * 64];
    unsigned short* const vd0 = &Vs[0][(w * 16) * 64];
    unsigned short* const vd1 = &Vs[1][(w * 16) * 64];

#define STAGE(KD, VD)                                                  \
    do {                                                               \
        gload_lds16(kp0, (KD));        gload_lds16(kp1, (KD) + 512);   \
        gload_lds16(vp0, (VD));        gload_lds16(vp1, (VD) + 512);   \
        kp0 += 64 * 2048; kp1 += 64 * 2048; vp0 += 64; vp1 += 64;      \
    } while (0)

    STAGE(kd0, vd0);

    for (int jt = 0; jt < 16; ++jt) {
        const int bb = jt & 1;
        __syncthreads();
        if (jt < 15) {
            if (bb) STAGE(kd0, vd0); else STAGE(kd1, vd1);
        }
        const unsigned short* KsB = &Ks[bb][0];
        const unsigned short* VsB = &Vs[bb][0];

        f32x16 stA, stB;
        __builtin_amdgcn_s_setprio(1);
        #pragma unroll
        for (int dc = 0; dc < 4; ++dc) {
            const bf16x8 kaA = *(const bf16x8*)&KsB[swzi(l31,      dc * 2 + hi)];
            const bf16x8 kaB = *(const bf16x8*)&KsB[swzi(32 + l31, dc * 2 + hi)];
            if (dc == 0) {
                stA = __builtin_amdgcn_mfma_f32_32x32x16_bf16(kaA, qf[0], zz, 0, 0, 0);
                stB = __builtin_amdgcn_mfma_f32_32x32x16_bf16(kaB, qf[0], zz, 0, 0, 0);
            } else {
                stA = __builtin_amdgcn_mfma_f32_32x32x16_bf16(kaA, qf[dc], stA, 0, 0, 0);
                stB = __builtin_amdgcn_mfma_f32_32x32x16_bf16(kaB, qf[dc], stB, 0, 0, 0);
            }
        }
        __builtin_amdgcn_s_setprio(0);

        #pragma unroll
        for (int x = 0; x < 2; ++x) {
            const f32x16& st = x ? stB : stA;
            float sum;
            unsigned wd[8];
            #pragma unroll
            for (int c = 0; c < 4; ++c) {
                const float e0 = fexp2(st[4 * c + 0]);
                const float e1 = fexp2(st[4 * c + 1]);
                const float e2 = fexp2(st[4 * c + 2]);
                const float e3 = fexp2(st[4 * c + 3]);
                const float s4 = (e0 + e1) + (e2 + e3);
                sum = c ? sum + s4 : s4;
                wd[2 * c]     = pkrtz(e0, e1);
                wd[2 * c + 1] = pkrtz(e2, e3);
            }
            lrun += sum;

            unsigned a0 = wd[0], a2 = wd[2];  pl32swap(a0, a2);
            unsigned a1 = wd[1], a3 = wd[3];  pl32swap(a1, a3);
            unsigned b0 = wd[4], b2 = wd[6];  pl32swap(b0, b2);
            unsigned b1 = wd[5], b3 = wd[7];  pl32swap(b1, b3);
            const u32x4 fva = {a0, a1, a2, a3};
            const u32x4 fvb = {b0, b1, b2, b3};
            const f16x8 pa0 = __builtin_bit_cast(f16x8, fva);
            const f16x8 pa1 = __builtin_bit_cast(f16x8, fvb);

            const int f0 = 2 * x;
            __builtin_amdgcn_s_setprio(1);
            {
                const f16x8 vb00 = *(const f16x8*)&VsB[swzi(l31,      f0 * 2 + hi)];
                const f16x8 vb01 = *(const f16x8*)&VsB[swzi(32 + l31, f0 * 2 + hi)];
                o0 = __builtin_amdgcn_mfma_f32_32x32x16_f16(pa0, vb00, o0, 0, 0, 0);
                o1 = __builtin_amdgcn_mfma_f32_32x32x16_f16(pa0, vb01, o1, 0, 0, 0);
                const f16x8 vb10 = *(const f16x8*)&VsB[swzi(l31,      (f0 + 1) * 2 + hi)];
                const f16x8 vb11 = *(const f16x8*)&VsB[swzi(32 + l31, (f0 + 1) * 2 + hi)];
                o0 = __builtin_amdgcn_mfma_f32_32x32x16_f16(pa1, vb10, o0, 0, 0, 0);
                o1 = __builtin_amdgcn_mfma_f32_32x32x16_f16(pa1, vb11, o1, 0, 0, 0);
            }
            __builtin_amdgcn_s_setprio(0);
        }
    }
#undef STAGE

    lrun += __shfl_xor(lrun, 32);
    const float inv = 1.0f / lrun;
    #pragma unroll
    for (int r = 0; r < 16; ++r) {
        const int qr = (r & 3) + 8 * (r >> 2) + 4 * hi;
        const float ir = __shfl(inv, qr);
        const int q = qt * 128 + w * 32 + qr;
        unsigned short* dst = PO + ((size_t)(b * TT + q)) * EMB + h * HDIM + l31;
        dst[0]  = f2h(o0[r] * ir);
        dst[32] = f2h(o1[r] * ir);
    }
    if (!hi) {
        const int q = qt * 128 + w * 32 + l31;
        PL[((size_t)(b * HEADS + h)) * TT + q] = lrun;
    }
}

// ---------------------------------------------------------------------------
// Merge the two key-half partials: AO = (Oa*la + Ob*lb) / (la+lb), bf16 out.
// ---------------------------------------------------------------------------
__global__ __launch_bounds__(256)
void merge_attn(const unsigned short* __restrict__ PO0,
                const unsigned short* __restrict__ PO1,
                const float* __restrict__ PL0,
                const float* __restrict__ PL1,
                unsigned short* __restrict__ AOb) {
    const int i = blockIdx.x * 256 + threadIdx.x;   // 4-elem group
    const int tg  = i >> 8;            // b*2048 + t
    const int col = (i & 255) * 4;
    const int h   = col >> 6;
    const int b   = tg >> 11, t = tg & 2047;

    const float la = PL0[((size_t)(b * HEADS + h)) * TT + t];
    const float lb = PL1[((size_t)(b * HEADS + h)) * TT + t];
    const float inv = 1.0f / (la + lb);
    const float wa = la * inv, wb = lb * inv;

    const ushort4 a = ((const ushort4*)PO0)[i];
    const ushort4 c = ((const ushort4*)PO1)[i];
    ushort4 o;
    o.x = f2bf(h2f(a.x) * wa + h2f(c.x) * wb);
    o.y = f2bf(h2f(a.y) * wa + h2f(c.y) * wb);
    o.z = f2bf(h2f(a.z) * wa + h2f(c.z) * wb);
    o.w = f2bf(h2f(a.w) * wa + h2f(c.w) * wb);
    ((ushort4*)AOb)[i] = o;
}

// ---------------------------------------------------------------------------
extern "C" void kernel_launch(void* const* d_in, const int* in_sizes, int n_in,
                              void* d_out, int out_size, void* d_ws, size_t ws_size,
                              hipStream_t stream) {
    const float* x    = (const float*)d_in[0];   // [2,2048,1024]
    const float* Wqkv = (const float*)d_in[1];   // [3072,1024]
    const float* Wout = (const float*)d_in[2];   // [1024,1024]
    float* out = (float*)d_out;

    unsigned short* Wqb = (unsigned short*)d_ws;   // 3145728 (permuted)
    unsigned short* Wob = Wqb + 3145728;           // 1048576
    unsigned short* xb  = Wob + 1048576;           // 4194304 (aliased by AOb)
    unsigned short* QKb = xb  + 4194304;           // 8388608 [b*t][2048] bf16
    unsigned short* Vt  = QKb + 8388608;           // 4194304 [b,h,d,t] fp16
    unsigned short* PO0 = Vt  + 4194304;           // 4194304 fp16 partial O
    unsigned short* PO1 = PO0 + 4194304;           // 4194304 fp16 partial O
    float*          PL0 = (float*)(PO1 + 4194304); // 65536 f32
    float*          PL1 = PL0 + 65536;             // 65536 f32
    unsigned short* AOb = xb;                      // reuse xb (dead after QKV)

    conv_all<<<6144, 256, 0, stream>>>(x, xb, Wqkv, Wqb, Wout, Wob);

    gemm_bf16<1><<<768, 256, 0, stream>>>(xb, Wqb, nullptr, QKb, Vt);

    attn32<<<dim3(32, 16, 2), 256, 0, stream>>>(QKb, Vt, PO0, PO1, PL0, PL1);

    merge_attn<<<4096, 256, 0, stream>>>(PO0, PO1, PL0, PL1, AOb);

    gemm_bf16<0><<<256, 256, 0, stream>>>(AOb, Wob, out, nullptr, nullptr);
}

// Round 17
// 126.055 us; speedup vs baseline: 1.0623x; 1.0298x over previous
//
#include <hip/hip_runtime.h>
#include <hip/hip_bf16.h>

// MHA b=2 t=2048 E=1024 h=16 d=64 (fp32 in/out).
// R17: consolidation -- revert to the best-measured configuration (R14,
//      126.2us): gemm256_qkv (256x192 fat tile, 2-phase), out-proj 128^2
//      2-buffer 2-phase, attn32 (R12: key-split + XCD swizzle, 46us),
//      conv_all, merge_attn.  No new experiments.

#define HEADS 16
#define EMB   1024
#define HDIM  64
#define BB    2
#define TT    2048
#define QSCALE 0.18033688011112042f   // (1/8) * log2(e)

typedef __attribute__((ext_vector_type(8)))  short      bf16x8;
typedef __attribute__((ext_vector_type(8)))  _Float16   f16x8;
typedef __attribute__((ext_vector_type(4)))  float      f32x4;
typedef __attribute__((ext_vector_type(16))) float      f32x16;
typedef __attribute__((ext_vector_type(4)))  unsigned   u32x4;

__device__ __forceinline__ unsigned short f2bf(float f) {
    __hip_bfloat16 h = __float2bfloat16(f);
    return __builtin_bit_cast(unsigned short, h);
}
__device__ __forceinline__ float fexp2(float x) {
#if __has_builtin(__builtin_amdgcn_exp2f)
    return __builtin_amdgcn_exp2f(x);
#else
    return exp2f(x);
#endif
}
__device__ __forceinline__ unsigned pkrtz(float a, float b) {
    auto r = __builtin_amdgcn_cvt_pkrtz(a, b);
    return __builtin_bit_cast(unsigned, r);
}
__device__ __forceinline__ unsigned short f2h(float f) {
    return (unsigned short)(pkrtz(f, 0.f) & 0xffffu);
}
__device__ __forceinline__ float h2f(unsigned short u) {
    return (float)__builtin_bit_cast(_Float16, u);
}
__device__ __forceinline__ void gload_lds16(const void* g, void* l) {
    __builtin_amdgcn_global_load_lds(
        (const __attribute__((address_space(1))) void*)g,
        (__attribute__((address_space(3))) void*)l, 16, 0, 0);
}
// swizzled ushort index into [rows][64]-short LDS tile (128B rows, 16B blocks)
__device__ __forceinline__ int swzi(int row, int blk) {
    return row * 64 + ((blk ^ (row & 7)) << 3);
}
// v_permlane32_swap_b32: a' = {a.lo32, b.lo32}, b' = {a.hi32, b.hi32}
__device__ __forceinline__ void pl32swap(unsigned& a, unsigned& b) {
    asm("v_permlane32_swap_b32 %0, %1" : "+v"(a), "+v"(b));
}

// ---------------------------------------------------------------------------
// Fused conversions: blocks 0..2047 x->xb; 2048..5119 Wqkv->Wqb (permuted);
// 5120..6143 Wout->Wob.
// ---------------------------------------------------------------------------
__global__ __launch_bounds__(256)
void conv_all(const float* __restrict__ x,    unsigned short* __restrict__ xb,
              const float* __restrict__ Wqkv, unsigned short* __restrict__ Wqb,
              const float* __restrict__ Wout, unsigned short* __restrict__ Wob) {
    const int blk = blockIdx.x;
    if (blk < 2048) {
        const int i = blk * 256 + threadIdx.x;      // 8 floats / thread
        const float4 v0 = ((const float4*)x)[i * 2];
        const float4 v1 = ((const float4*)x)[i * 2 + 1];
        ushort4 a, b;
        a.x = f2bf(v0.x); a.y = f2bf(v0.y); a.z = f2bf(v0.z); a.w = f2bf(v0.w);
        b.x = f2bf(v1.x); b.y = f2bf(v1.y); b.z = f2bf(v1.z); b.w = f2bf(v1.w);
        ((ushort4*)xb)[i * 2]     = a;
        ((ushort4*)xb)[i * 2 + 1] = b;
    } else if (blk < 5120) {
        const int np = blk - 2048;
        const int ns = (np & 63) * 48 + (np >> 10) * 16 + ((np >> 6) & 15);
        const float4 v = ((const float4*)(Wqkv + (size_t)ns * 1024))[threadIdx.x];
        ushort4 u;
        u.x = f2bf(v.x); u.y = f2bf(v.y); u.z = f2bf(v.z); u.w = f2bf(v.w);
        ((ushort4*)(Wqb + (size_t)np * 1024))[threadIdx.x] = u;
    } else {
        const int np = blk - 5120;
        const float4 v = ((const float4*)(Wout + (size_t)np * 1024))[threadIdx.x];
        ushort4 u;
        u.x = f2bf(v.x); u.y = f2bf(v.y); u.z = f2bf(v.z); u.w = f2bf(v.w);
        ((ushort4*)(Wob + (size_t)np * 1024))[threadIdx.x] = u;
    }
}

// ---------------------------------------------------------------------------
// QKV GEMM, 256x192 tile, BK=64, 512 threads (8 waves, 2m x 4n).
// D[n][m] = sum_k W[n,k]*x[m,k]; per wave 128x48 (8 mi x 3 ni frags 16x16x32).
// 2-phase: vmcnt(0) -> barrier -> STAGE(next) -> compute(cur).
// Epilogue per-ni: np<1024 Q(*QSCALE)->QKb; np<2048 K->QKb; else V->Vt fp16.
// ---------------------------------------------------------------------------
__global__ __launch_bounds__(512, 2)
void gemm256_qkv(const unsigned short* __restrict__ Ag,
                 const unsigned short* __restrict__ Wg,
                 unsigned short* __restrict__ QKb,
                 unsigned short* __restrict__ Vt) {
    __shared__ __align__(16) unsigned short AbL[2][256 * 64];  // 32KB each
    __shared__ __align__(16) unsigned short BbL[2][192 * 64];  // 24KB each

    const int tid = threadIdx.x, lane = tid & 63, w = tid >> 6;   // w 0..7
    const int n0 = blockIdx.x * 192, m0 = blockIdx.y * 256;
    const int wm = (w >> 2) * 128;        // 0 / 128
    const int wn = (w & 3) * 48;          // 0 / 48 / 96 / 144
    const int r16 = lane & 15, g = lane >> 4, gq = g * 4;

    f32x4 acc[8][3];
    #pragma unroll
    for (int i = 0; i < 8; ++i)
        #pragma unroll
        for (int j = 0; j < 3; ++j)
            acc[i][j] = (f32x4){0.f, 0.f, 0.f, 0.f};

    // staging: per gload a wave covers 8 consecutive rows x 128B.
    const int srl = lane >> 3;
    const int scol = ((lane & 7) ^ srl) << 3;                  // shorts
    const unsigned short* Asrc = Ag + (size_t)(m0 + w * 32 + srl) * 1024 + scol;
    const unsigned short* Bsrc = Wg + (size_t)(n0 + w * 24 + srl) * 1024 + scol;

#define STAGE256(AB, BB, K0)                                                \
    do {                                                                    \
        _Pragma("unroll")                                                   \
        for (int i = 0; i < 4; ++i)                                         \
            gload_lds16(Asrc + (K0) + i * 8192,                             \
                        (AB) + (w * 32 + i * 8) * 64);                      \
        _Pragma("unroll")                                                   \
        for (int i = 0; i < 3; ++i)                                         \
            gload_lds16(Bsrc + (K0) + i * 8192,                             \
                        (BB) + (w * 24 + i * 8) * 64);                      \
    } while (0)

    unsigned short *pa0 = &AbL[0][0], *pa1 = &AbL[1][0];
    unsigned short *pb0 = &BbL[0][0], *pb1 = &BbL[1][0];

    STAGE256(pa0, pb0, 0);

    for (int kt = 0; kt < 16; ++kt) {
        asm volatile("s_waitcnt vmcnt(0)" ::: "memory");
        __builtin_amdgcn_s_barrier();
        if (kt < 15) STAGE256(pa1, pb1, (kt + 1) * 64);

        __builtin_amdgcn_s_setprio(1);
        #pragma unroll
        for (int ks = 0; ks < 2; ++ks) {
            bf16x8 bf[3];
            #pragma unroll
            for (int ni = 0; ni < 3; ++ni)
                bf[ni] = *(const bf16x8*)&pb0[swzi(wn + ni * 16 + r16, ks * 4 + g)];
            #pragma unroll
            for (int mi = 0; mi < 8; ++mi) {
                const bf16x8 xf = *(const bf16x8*)&pa0[swzi(wm + mi * 16 + r16, ks * 4 + g)];
                #pragma unroll
                for (int ni = 0; ni < 3; ++ni)
                    acc[mi][ni] = __builtin_amdgcn_mfma_f32_16x16x32_bf16(
                        bf[ni], xf, acc[mi][ni], 0, 0, 0);
            }
        }
        __builtin_amdgcn_s_setprio(0);

        unsigned short* t;
        t = pa0; pa0 = pa1; pa1 = t;
        t = pb0; pb0 = pb1; pb1 = t;
    }
#undef STAGE256

    // epilogue: per-ni region select (16 | 1024 so each frag is uniform)
    #pragma unroll
    for (int ni = 0; ni < 3; ++ni) {
        const int npb = n0 + wn + ni * 16;   // frag n-base (16-aligned)
        if (npb < 2048) {
            const float qs = npb < 1024 ? QSCALE : 1.0f;
            #pragma unroll
            for (int mi = 0; mi < 8; ++mi) {
                const int m = m0 + wm + mi * 16 + r16;
                ushort4 u;
                u.x = f2bf(acc[mi][ni][0] * qs); u.y = f2bf(acc[mi][ni][1] * qs);
                u.z = f2bf(acc[mi][ni][2] * qs); u.w = f2bf(acc[mi][ni][3] * qs);
                *(ushort4*)&QKb[(size_t)m * 2048 + npb + gq] = u;
            }
        } else {
            #pragma unroll
            for (int mi = 0; mi < 8; ++mi) {
                const int m  = m0 + wm + mi * 16 + r16;
                const int b  = m >> 11, tt = m & 2047;
                const int nv0 = npb - 2048 + gq;
                #pragma unroll
                for (int j = 0; j < 4; ++j) {
                    const int nv = nv0 + j, h = nv >> 6, d = nv & 63;
                    Vt[(((size_t)(b * HEADS + h)) * HDIM + d) * TT + tt] =
                        f2h(acc[mi][ni][j]);
                }
            }
        }
    }
}

// ---------------------------------------------------------------------------
// Out-proj GEMM (128^2, 2-buffer 2-phase).
// ---------------------------------------------------------------------------
__global__ __launch_bounds__(256)
void gemm_bf16(const unsigned short* __restrict__ Ag,
               const unsigned short* __restrict__ Wg,
               float* __restrict__ Cout) {
    __shared__ __align__(16) unsigned short AbL[2][128 * 32];
    __shared__ __align__(16) unsigned short WbL[2][128 * 32];

    const int tid = threadIdx.x, lane = tid & 63, w = tid >> 6;
    const int n0 = blockIdx.x * 128, m0 = blockIdx.y * 128;
    const int wn = (w >> 1) * 64, wm = (w & 1) * 64;
    const int r16 = lane & 15, g = lane >> 4;
    const int goff = ((g ^ ((r16 >> 1) & 3)) << 3);

    f32x4 acc[4][4];
    #pragma unroll
    for (int i = 0; i < 4; ++i)
        #pragma unroll
        for (int j = 0; j < 4; ++j)
            acc[i][j] = (f32x4){0.f, 0.f, 0.f, 0.f};

    const int srow = w * 16 + (lane >> 2);
    const int scol = ((lane & 3) ^ ((lane >> 3) & 3)) << 3;
    const int sdst = (w * 16) * 32;
    const unsigned short* Asrc = Ag + (size_t)(m0 + srow) * 1024 + scol;
    const unsigned short* Wsrc = Wg + (size_t)(n0 + srow) * 1024 + scol;

#define STAGE(AB, WB, K0)                                            \
    do {                                                             \
        gload_lds16(Asrc + (K0),              (AB) + sdst);          \
        gload_lds16(Asrc + (K0) + 64 * 1024,  (AB) + sdst + 2048);   \
        gload_lds16(Wsrc + (K0),              (WB) + sdst);          \
        gload_lds16(Wsrc + (K0) + 64 * 1024,  (WB) + sdst + 2048);   \
    } while (0)

    unsigned short *pa0 = &AbL[0][0], *pa1 = &AbL[1][0];
    unsigned short *pw0 = &WbL[0][0], *pw1 = &WbL[1][0];

    STAGE(pa0, pw0, 0);

    for (int kt = 0; kt < 32; ++kt) {
        asm volatile("s_waitcnt vmcnt(0)" ::: "memory");
        __builtin_amdgcn_s_barrier();
        if (kt < 31) STAGE(pa1, pw1, (kt + 1) * 32);

        bf16x8 xf[4];
        #pragma unroll
        for (int mi = 0; mi < 4; ++mi)
            xf[mi] = *(const bf16x8*)&pa0[(wm + mi * 16 + r16) * 32 + goff];
        __builtin_amdgcn_s_setprio(1);
        #pragma unroll
        for (int ni = 0; ni < 4; ++ni) {
            const bf16x8 wf = *(const bf16x8*)&pw0[(wn + ni * 16 + r16) * 32 + goff];
            #pragma unroll
            for (int mi = 0; mi < 4; ++mi)
                acc[ni][mi] = __builtin_amdgcn_mfma_f32_16x16x32_bf16(
                    wf, xf[mi], acc[ni][mi], 0, 0, 0);
        }
        __builtin_amdgcn_s_setprio(0);

        unsigned short* t;
        t = pa0; pa0 = pa1; pa1 = t;
        t = pw0; pw0 = pw1; pw1 = t;
    }
#undef STAGE

    const int gq = g * 4;
    #pragma unroll
    for (int ni = 0; ni < 4; ++ni)
        #pragma unroll
        for (int mi = 0; mi < 4; ++mi) {
            const int m = m0 + wm + mi * 16 + r16;
            *(f32x4*)&Cout[(size_t)m * 1024 + (n0 + wn + ni * 16 + gq)] =
                acc[ni][mi];
        }
}

// ---------------------------------------------------------------------------
// Flash attention, 32x32x16 MFMA, 2-way key split (R12-verified: 46us).
// ---------------------------------------------------------------------------
__global__ __launch_bounds__(256, 4)
void attn32(const unsigned short* __restrict__ QKb,
            const unsigned short* __restrict__ Vt,
            unsigned short* __restrict__ PO0,
            unsigned short* __restrict__ PO1,
            float* __restrict__ PL0,
            float* __restrict__ PL1) {
    __shared__ __align__(16) unsigned short Ks[2][64 * 64];
    __shared__ __align__(16) unsigned short Vs[2][64 * 64];

    const int tid = threadIdx.x, lane = tid & 63, w = tid >> 6;
    const int l31 = lane & 31, hi = lane >> 5;
    const int bid = blockIdx.x + 32 * blockIdx.y + 512 * blockIdx.z;  // 0..1023
    const int vb  = (bid & 7) * 128 + (bid >> 3);
    const int qt  = vb & 15, kh = (vb >> 4) & 1;
    const int h   = (vb >> 5) & 15, b = vb >> 9;
    const int kbase = kh * 1024;
    const unsigned short* Vsrc = Vt + (size_t)(b * HEADS + h) * HDIM * TT;
    unsigned short* PO = kh ? PO1 : PO0;
    float*          PL = kh ? PL1 : PL0;

    bf16x8 qf[4];
    {
        const unsigned short* qrow =
            QKb + ((size_t)(b * TT + qt * 128 + w * 32 + l31)) * 2048 + h * HDIM;
        #pragma unroll
        for (int dc = 0; dc < 4; ++dc)
            qf[dc] = *(const bf16x8*)(qrow + dc * 16 + hi * 8);
    }

    const f32x16 zz = {};
    f32x16 o0 = {}, o1 = {};
    float lrun = 0.f;

    const int srl = lane >> 3;
    const int scb = lane & 7;
    const int cbs = (scb ^ srl) << 3;
    const int rl0 = w * 16 + srl;
    const unsigned short* kp0 =
        QKb + (size_t)(b * TT + kbase + rl0) * 2048 + 1024 + h * HDIM + cbs;
    const unsigned short* kp1 = kp0 + (size_t)8 * 2048;
    const unsigned short* vp0 = Vsrc + (size_t)rl0 * TT + kbase + cbs;
    const unsigned short* vp1 = vp0 + (size_t)8 * TT;
    unsigned short* const kd0 = &Ks[0][(w * 16) * 64];
    unsigned short* const kd1 = &Ks[1][(w * 16) * 64];
    unsigned short* const vd0 = &Vs[0][(w * 16) * 64];
    unsigned short* const vd1 = &Vs[1][(w * 16) * 64];

#define STAGE(KD, VD)                                                  \
    do {                                                               \
        gload_lds16(kp0, (KD));        gload_lds16(kp1, (KD) + 512);   \
        gload_lds16(vp0, (VD));        gload_lds16(vp1, (VD) + 512);   \
        kp0 += 64 * 2048; kp1 += 64 * 2048; vp0 += 64; vp1 += 64;      \
    } while (0)

    STAGE(kd0, vd0);

    for (int jt = 0; jt < 16; ++jt) {
        const int bb = jt & 1;
        __syncthreads();
        if (jt < 15) {
            if (bb) STAGE(kd0, vd0); else STAGE(kd1, vd1);
        }
        const unsigned short* KsB = &Ks[bb][0];
        const unsigned short* VsB = &Vs[bb][0];

        f32x16 stA, stB;
        __builtin_amdgcn_s_setprio(1);
        #pragma unroll
        for (int dc = 0; dc < 4; ++dc) {
            const bf16x8 kaA = *(const bf16x8*)&KsB[swzi(l31,      dc * 2 + hi)];
            const bf16x8 kaB = *(const bf16x8*)&KsB[swzi(32 + l31, dc * 2 + hi)];
            if (dc == 0) {
                stA = __builtin_amdgcn_mfma_f32_32x32x16_bf16(kaA, qf[0], zz, 0, 0, 0);
                stB = __builtin_amdgcn_mfma_f32_32x32x16_bf16(kaB, qf[0], zz, 0, 0, 0);
            } else {
                stA = __builtin_amdgcn_mfma_f32_32x32x16_bf16(kaA, qf[dc], stA, 0, 0, 0);
                stB = __builtin_amdgcn_mfma_f32_32x32x16_bf16(kaB, qf[dc], stB, 0, 0, 0);
            }
        }
        __builtin_amdgcn_s_setprio(0);

        #pragma unroll
        for (int x = 0; x < 2; ++x) {
            const f32x16& st = x ? stB : stA;
            float sum;
            unsigned wd[8];
            #pragma unroll
            for (int c = 0; c < 4; ++c) {
                const float e0 = fexp2(st[4 * c + 0]);
                const float e1 = fexp2(st[4 * c + 1]);
                const float e2 = fexp2(st[4 * c + 2]);
                const float e3 = fexp2(st[4 * c + 3]);
                const float s4 = (e0 + e1) + (e2 + e3);
                sum = c ? sum + s4 : s4;
                wd[2 * c]     = pkrtz(e0, e1);
                wd[2 * c + 1] = pkrtz(e2, e3);
            }
            lrun += sum;

            unsigned a0 = wd[0], a2 = wd[2];  pl32swap(a0, a2);
            unsigned a1 = wd[1], a3 = wd[3];  pl32swap(a1, a3);
            unsigned b0 = wd[4], b2 = wd[6];  pl32swap(b0, b2);
            unsigned b1 = wd[5], b3 = wd[7];  pl32swap(b1, b3);
            const u32x4 fva = {a0, a1, a2, a3};
            const u32x4 fvb = {b0, b1, b2, b3};
            const f16x8 pa0 = __builtin_bit_cast(f16x8, fva);
            const f16x8 pa1 = __builtin_bit_cast(f16x8, fvb);

            const int f0 = 2 * x;
            __builtin_amdgcn_s_setprio(1);
            {
                const f16x8 vb00 = *(const f16x8*)&VsB[swzi(l31,      f0 * 2 + hi)];
                const f16x8 vb01 = *(const f16x8*)&VsB[swzi(32 + l31, f0 * 2 + hi)];
                o0 = __builtin_amdgcn_mfma_f32_32x32x16_f16(pa0, vb00, o0, 0, 0, 0);
                o1 = __builtin_amdgcn_mfma_f32_32x32x16_f16(pa0, vb01, o1, 0, 0, 0);
                const f16x8 vb10 = *(const f16x8*)&VsB[swzi(l31,      (f0 + 1) * 2 + hi)];
                const f16x8 vb11 = *(const f16x8*)&VsB[swzi(32 + l31, (f0 + 1) * 2 + hi)];
                o0 = __builtin_amdgcn_mfma_f32_32x32x16_f16(pa1, vb10, o0, 0, 0, 0);
                o1 = __builtin_amdgcn_mfma_f32_32x32x16_f16(pa1, vb11, o1, 0, 0, 0);
            }
            __builtin_amdgcn_s_setprio(0);
        }
    }
#undef STAGE

    lrun += __shfl_xor(lrun, 32);
    const float inv = 1.0f / lrun;
    #pragma unroll
    for (int r = 0; r < 16; ++r) {
        const int qr = (r & 3) + 8 * (r >> 2) + 4 * hi;
        const float ir = __shfl(inv, qr);
        const int q = qt * 128 + w * 32 + qr;
        unsigned short* dst = PO + ((size_t)(b * TT + q)) * EMB + h * HDIM + l31;
        dst[0]  = f2h(o0[r] * ir);
        dst[32] = f2h(o1[r] * ir);
    }
    if (!hi) {
        const int q = qt * 128 + w * 32 + l31;
        PL[((size_t)(b * HEADS + h)) * TT + q] = lrun;
    }
}

// ---------------------------------------------------------------------------
// Merge the two key-half partials: AO = (Oa*la + Ob*lb) / (la+lb), bf16 out.
// ---------------------------------------------------------------------------
__global__ __launch_bounds__(256)
void merge_attn(const unsigned short* __restrict__ PO0,
                const unsigned short* __restrict__ PO1,
                const float* __restrict__ PL0,
                const float* __restrict__ PL1,
                unsigned short* __restrict__ AOb) {
    const int i = blockIdx.x * 256 + threadIdx.x;   // 4-elem group
    const int tg  = i >> 8;            // b*2048 + t
    const int col = (i & 255) * 4;
    const int h   = col >> 6;
    const int b   = tg >> 11, t = tg & 2047;

    const float la = PL0[((size_t)(b * HEADS + h)) * TT + t];
    const float lb = PL1[((size_t)(b * HEADS + h)) * TT + t];
    const float inv = 1.0f / (la + lb);
    const float wa = la * inv, wb = lb * inv;

    const ushort4 a = ((const ushort4*)PO0)[i];
    const ushort4 c = ((const ushort4*)PO1)[i];
    ushort4 o;
    o.x = f2bf(h2f(a.x) * wa + h2f(c.x) * wb);
    o.y = f2bf(h2f(a.y) * wa + h2f(c.y) * wb);
    o.z = f2bf(h2f(a.z) * wa + h2f(c.z) * wb);
    o.w = f2bf(h2f(a.w) * wa + h2f(c.w) * wb);
    ((ushort4*)AOb)[i] = o;
}

// ---------------------------------------------------------------------------
extern "C" void kernel_launch(void* const* d_in, const int* in_sizes, int n_in,
                              void* d_out, int out_size, void* d_ws, size_t ws_size,
                              hipStream_t stream) {
    const float* x    = (const float*)d_in[0];   // [2,2048,1024]
    const float* Wqkv = (const float*)d_in[1];   // [3072,1024]
    const float* Wout = (const float*)d_in[2];   // [1024,1024]
    float* out = (float*)d_out;

    unsigned short* Wqb = (unsigned short*)d_ws;   // 3145728 (permuted)
    unsigned short* Wob = Wqb + 3145728;           // 1048576
    unsigned short* xb  = Wob + 1048576;           // 4194304 (aliased by AOb)
    unsigned short* QKb = xb  + 4194304;           // 8388608 [b*t][2048] bf16
    unsigned short* Vt  = QKb + 8388608;           // 4194304 [b,h,d,t] fp16
    unsigned short* PO0 = Vt  + 4194304;           // 4194304 fp16 partial O
    unsigned short* PO1 = PO0 + 4194304;           // 4194304 fp16 partial O
    float*          PL0 = (float*)(PO1 + 4194304); // 65536 f32
    float*          PL1 = PL0 + 65536;             // 65536 f32
    unsigned short* AOb = xb;                      // reuse xb (dead after QKV)

    conv_all<<<6144, 256, 0, stream>>>(x, xb, Wqkv, Wqb, Wout, Wob);

    gemm256_qkv<<<dim3(16, 16), 512, 0, stream>>>(xb, Wqb, QKb, Vt);

    attn32<<<dim3(32, 16, 2), 256, 0, stream>>>(QKb, Vt, PO0, PO1, PL0, PL1);

    merge_attn<<<4096, 256, 0, stream>>>(PO0, PO1, PL0, PL1, AOb);

    gemm_bf16<<<dim3(8, 32), 256, 0, stream>>>(AOb, Wob, out);
}